// Round 1
// baseline (270.814 us; speedup 1.0000x reference)
//
#include <hip/hip_runtime.h>

// Propagation: E = softsign(V V^T / sqrt(D)); out0 = E @ state; out1 = E @ V
// B=4, N=4096, D=256, fp32 in/out. Fused flash-style, bf16 MFMA.
//
// Design notes (round 0):
// - BM=BJ=64, 256 threads (4 waves), grid = 4*64 = 256 blocks (1/CU).
// - LDS: vi/vj row-major bf16 stride 264 (132 words = 4 mod 32 banks -> ~2-way, free);
//   vjt = d-major copy for GEMM2 B-operand, 16B blocks XOR-swizzled (jb ^ (d&7));
//   Esh bf16 stride 72 (36 words = 4 mod 32).
// - GEMM1 = gemm_bt(val_i, val_j): A-frag m=lane&15 k=quad*8+j, B-frag n=lane&15.
// - E round-trips through LDS (C-layout -> A-layout), per verified m120 pattern.
// - delta_state: per-lane fp32 FMA vs staged state tile, shfl_xor(1,2,4,8) reduce
//   over the 16 column-lanes, cross-wave-pair sum via small LDS buffer.

#define B_  4
#define N_  4096
#define D_  256

typedef __attribute__((ext_vector_type(8))) short short8;
typedef __attribute__((ext_vector_type(4))) float floatx4;

__device__ __forceinline__ unsigned short f2bf(float f) {
    unsigned int u = __float_as_uint(f);
    u += 0x7fff + ((u >> 16) & 1);   // round-to-nearest-even
    return (unsigned short)(u >> 16);
}

__global__ __launch_bounds__(256, 1)
void prop_kernel(const float* __restrict__ val,
                 const float* __restrict__ state,
                 float* __restrict__ out) {
    __shared__ __attribute__((aligned(16))) unsigned short vi[64][264];   // 33.8 KB
    __shared__ __attribute__((aligned(16))) unsigned short vj[64][264];   // 33.8 KB
    __shared__ __attribute__((aligned(16))) unsigned short vjt[2048][8];  // 32 KB, blk = d*8 + (jb^(d&7))
    __shared__ __attribute__((aligned(16))) unsigned short Esh[64][72];   // 9.2 KB
    __shared__ float stj[64];
    __shared__ float dsred[2][64];

    const int t    = threadIdx.x;
    const int w    = t >> 6;
    const int lane = t & 63;
    const int quad = lane >> 4;
    const int l16  = lane & 15;

    const int b   = blockIdx.x >> 6;
    const int it0 = (blockIdx.x & 63) << 6;

    const float* valb = val   + (size_t)b * N_ * D_;
    const float* stb  = state + (size_t)b * N_;

    // ---- load + convert the i-tile once ----
    #pragma unroll
    for (int n = 0; n < 16; ++n) {
        int idx = t + 256 * n;
        int row = idx >> 6;
        int c4  = idx & 63;
        float4 v = *(const float4*)(valb + (size_t)(it0 + row) * D_ + c4 * 4);
        ushort4 h;
        h.x = f2bf(v.x); h.y = f2bf(v.y); h.z = f2bf(v.z); h.w = f2bf(v.w);
        *(ushort4*)&vi[row][c4 * 4] = h;
    }

    const int r0 = (w >> 1) * 32;   // GEMM1 row base for this wave
    const int c0 = (w & 1) * 32;    // GEMM1 col base for this wave

    floatx4 dv[4][4];               // delta_val accumulator: [row-tile][col-tile]
    #pragma unroll
    for (int a = 0; a < 4; ++a)
        #pragma unroll
        for (int c = 0; c < 4; ++c)
            dv[a][c] = (floatx4){0.f, 0.f, 0.f, 0.f};
    float dsp[8];                   // delta_state partials [a*4+r]
    #pragma unroll
    for (int k = 0; k < 8; ++k) dsp[k] = 0.f;

    for (int jt = 0; jt < 64; ++jt) {
        const int j0 = jt * 64;

        // ---- stage V_j tile (fp32 -> bf16, coalesced) ----
        #pragma unroll
        for (int n = 0; n < 16; ++n) {
            int idx = t + 256 * n;
            int row = idx >> 6;
            int c4  = idx & 63;
            float4 v = *(const float4*)(valb + (size_t)(j0 + row) * D_ + c4 * 4);
            ushort4 h;
            h.x = f2bf(v.x); h.y = f2bf(v.y); h.z = f2bf(v.z); h.w = f2bf(v.w);
            *(ushort4*)&vj[row][c4 * 4] = h;
        }
        if (t < 64) stj[t] = stb[j0 + t];
        __syncthreads();   // B1: vj/stj visible

        // ---- LDS transpose vj -> vjt (d-major, 8-j blocks, XOR swizzled) ----
        #pragma unroll
        for (int n = 0; n < 8; ++n) {
            const int d  = t;       // 0..255
            const int jb = n;       // 0..7
            short8 pk;
            #pragma unroll
            for (int jj = 0; jj < 8; ++jj) pk[jj] = (short)vj[jb * 8 + jj][d];
            *(short8*)&vjt[d * 8 + (jb ^ (d & 7))][0] = pk;
        }

        // ---- GEMM1: S[64][64] = Vi . Vj^T (K = 256) ----
        floatx4 sa[2][2];
        #pragma unroll
        for (int a = 0; a < 2; ++a)
            #pragma unroll
            for (int c = 0; c < 2; ++c)
                sa[a][c] = (floatx4){0.f, 0.f, 0.f, 0.f};

        #pragma unroll
        for (int ks = 0; ks < 8; ++ks) {
            const int d0 = ks * 32 + quad * 8;
            short8 a0 = *(const short8*)&vi[r0 + l16][d0];
            short8 a1 = *(const short8*)&vi[r0 + 16 + l16][d0];
            short8 b0 = *(const short8*)&vj[c0 + l16][d0];
            short8 b1 = *(const short8*)&vj[c0 + 16 + l16][d0];
            sa[0][0] = __builtin_amdgcn_mfma_f32_16x16x32_bf16(a0, b0, sa[0][0], 0, 0, 0);
            sa[0][1] = __builtin_amdgcn_mfma_f32_16x16x32_bf16(a0, b1, sa[0][1], 0, 0, 0);
            sa[1][0] = __builtin_amdgcn_mfma_f32_16x16x32_bf16(a1, b0, sa[1][0], 0, 0, 0);
            sa[1][1] = __builtin_amdgcn_mfma_f32_16x16x32_bf16(a1, b1, sa[1][1], 0, 0, 0);
        }

        // ---- softsign epilogue: E to LDS (bf16) + delta_state partials (fp32) ----
        float stc0 = stj[c0 + l16];
        float stc1 = stj[c0 + 16 + l16];
        #pragma unroll
        for (int a = 0; a < 2; ++a) {
            #pragma unroll
            for (int r = 0; r < 4; ++r) {
                const int il = r0 + a * 16 + quad * 4 + r;
                float s0 = sa[a][0][r] * 0.0625f;
                float s1 = sa[a][1][r] * 0.0625f;
                float e0 = s0 / (1.0f + fabsf(s0));
                float e1 = s1 / (1.0f + fabsf(s1));
                dsp[a * 4 + r] += e0 * stc0 + e1 * stc1;
                Esh[il][c0 + l16]      = f2bf(e0);
                Esh[il][c0 + 16 + l16] = f2bf(e1);
            }
        }
        __syncthreads();   // B2: Esh/vjt visible

        // ---- GEMM2: dval[64][256] += E[64][64] . Vj[64][256] (K = 64) ----
        #pragma unroll
        for (int ks = 0; ks < 2; ++ks) {
            short8 af[4], bfr[4];
            #pragma unroll
            for (int a2 = 0; a2 < 4; ++a2)
                af[a2] = *(const short8*)&Esh[a2 * 16 + l16][ks * 32 + quad * 8];
            #pragma unroll
            for (int c2 = 0; c2 < 4; ++c2) {
                const int d  = w * 64 + c2 * 16 + l16;
                const int jb = ks * 4 + quad;
                bfr[c2] = *(const short8*)&vjt[d * 8 + (jb ^ (d & 7))][0];
            }
            #pragma unroll
            for (int a2 = 0; a2 < 4; ++a2)
                #pragma unroll
                for (int c2 = 0; c2 < 4; ++c2)
                    dv[a2][c2] = __builtin_amdgcn_mfma_f32_16x16x32_bf16(af[a2], bfr[c2], dv[a2][c2], 0, 0, 0);
        }
        // next iteration's staging writes vj/stj only (not read after B2) -> 2 barriers/iter
    }

    // ---- epilogue: delta_val ----
    float* dvo = out + (size_t)B_ * N_ + (size_t)b * N_ * D_;
    #pragma unroll
    for (int a2 = 0; a2 < 4; ++a2)
        #pragma unroll
        for (int c2 = 0; c2 < 4; ++c2)
            #pragma unroll
            for (int r = 0; r < 4; ++r) {
                const int i = it0 + a2 * 16 + quad * 4 + r;
                const int d = w * 64 + c2 * 16 + l16;
                dvo[(size_t)i * D_ + d] = dv[a2][c2][r];
            }

    // ---- epilogue: delta_state (reduce 16 column-lanes, then wave pairs) ----
    #pragma unroll
    for (int k = 0; k < 8; ++k) {
        float v = dsp[k];
        v += __shfl_xor(v, 1);
        v += __shfl_xor(v, 2);
        v += __shfl_xor(v, 4);
        v += __shfl_xor(v, 8);
        dsp[k] = v;
    }
    if (l16 == 0) {
        #pragma unroll
        for (int a = 0; a < 2; ++a)
            #pragma unroll
            for (int r = 0; r < 4; ++r) {
                const int row = (w >> 1) * 32 + a * 16 + quad * 4 + r;
                dsred[w & 1][row] = dsp[a * 4 + r];
            }
    }
    __syncthreads();
    if (t < 64) out[(size_t)b * N_ + it0 + t] = dsred[0][t] + dsred[1][t];
}

extern "C" void kernel_launch(void* const* d_in, const int* in_sizes, int n_in,
                              void* d_out, int out_size, void* d_ws, size_t ws_size,
                              hipStream_t stream) {
    const float* val   = (const float*)d_in[0];
    const float* state = (const float*)d_in[1];
    float* out = (float*)d_out;
    prop_kernel<<<dim3(256), dim3(256), 0, stream>>>(val, state, out);
}

// Round 2
// 211.514 us; speedup vs baseline: 1.2804x; 1.2804x over previous
//
#include <hip/hip_runtime.h>

// Propagation: E = softsign(V V^T / sqrt(D)); out0 = E @ state; out1 = E @ V
// B=4, N=4096, D=256, fp32 in/out.
//
// Round 2: two-kernel scheme.
//  - prepass: val fp32 -> Vb bf16 [B][N][D] and VT bf16 [B][D][N] in d_ws (16 MB).
//  - main: fused flash-style, stages vi/vj/vjt via global_load_lds width=16
//    (XOR-granule swizzle applied on the GLOBAL source address; LDS dest is
//    wave-uniform base + lane*16). vjt double-buffered so staging of iter k+1
//    issues after B2(k) and hides behind GEMM2(k). Softsign via v_rcp_f32.
//  - fallback: round-1 single kernel if ws_size < 16 MB.

#define B_  4
#define N_  4096
#define D_  256

typedef __attribute__((ext_vector_type(8))) short short8;
typedef __attribute__((ext_vector_type(4))) float floatx4;

__device__ __forceinline__ unsigned short f2bf(float f) {
    unsigned int u = __float_as_uint(f);
    u += 0x7fff + ((u >> 16) & 1);   // RTNE
    return (unsigned short)(u >> 16);
}

__device__ __forceinline__ void gl_lds16(const void* g, void* l) {
    __builtin_amdgcn_global_load_lds(
        (const __attribute__((address_space(1))) unsigned int*)g,
        (__attribute__((address_space(3))) unsigned int*)l, 16, 0, 0);
}
__device__ __forceinline__ void gl_lds4(const void* g, void* l) {
    __builtin_amdgcn_global_load_lds(
        (const __attribute__((address_space(1))) unsigned int*)g,
        (__attribute__((address_space(3))) unsigned int*)l, 4, 0, 0);
}

// ---------------- pre-pass: fp32 -> bf16, plus transpose ----------------
__global__ __launch_bounds__(256)
void prepass_kernel(const float* __restrict__ val,
                    unsigned short* __restrict__ Vb,
                    unsigned short* __restrict__ VT) {
    __shared__ unsigned short tile[64][68];
    const int t   = threadIdx.x;
    const int blk = blockIdx.x;            // b*256 + it*4 + dt
    const int b   = blk >> 8;
    const int it  = (blk >> 2) & 63;
    const int dt  = blk & 3;
    const int i0  = it * 64, d0 = dt * 64;
    const float*    vb  = val + (size_t)b * N_ * D_;
    unsigned short* Vbb = Vb  + (size_t)b * N_ * D_;
    unsigned short* VTb = VT  + (size_t)b * D_ * N_;

    #pragma unroll
    for (int q = 0; q < 4; ++q) {
        int idx = t + 256 * q;             // 1024 float4s = 64x64 tile
        int row = idx >> 4;                // 16 float4 per row
        int c4  = idx & 15;
        float4 v = *(const float4*)(vb + (size_t)(i0 + row) * D_ + d0 + c4 * 4);
        ushort4 h;
        h.x = f2bf(v.x); h.y = f2bf(v.y); h.z = f2bf(v.z); h.w = f2bf(v.w);
        *(ushort4*)(Vbb + (size_t)(i0 + row) * D_ + d0 + c4 * 4) = h;
        *(ushort4*)&tile[row][c4 * 4] = h;
    }
    __syncthreads();
    #pragma unroll
    for (int q = 0; q < 4; ++q) {
        int dr = (t >> 4) + q * 16;        // 0..63 (d within tile)
        int i4 = t & 15;
        ushort4 h;
        h.x = tile[i4 * 4 + 0][dr];
        h.y = tile[i4 * 4 + 1][dr];
        h.z = tile[i4 * 4 + 2][dr];
        h.w = tile[i4 * 4 + 3][dr];
        *(ushort4*)(VTb + (size_t)(d0 + dr) * N_ + i0 + i4 * 4) = h;
    }
}

// ---------------- main fused kernel ----------------
__global__ __launch_bounds__(256, 1)
void prop_main(const float* __restrict__ state,
               const unsigned short* __restrict__ Vb,
               const unsigned short* __restrict__ VT,
               float* __restrict__ out) {
    // vi/vj: [64 rows][256 d] bf16, granule(16B)-swizzled: granule g of row r at pos g^(r&7)
    // vjt  : [256 d rows][64 j] bf16, granule g of row d at pos g^(d&7); double-buffered
    __shared__ __attribute__((aligned(16))) unsigned short vi[64 * 256];     // 32 KB
    __shared__ __attribute__((aligned(16))) unsigned short vj[64 * 256];     // 32 KB
    __shared__ __attribute__((aligned(16))) unsigned short vjt[2 * 16384];   // 64 KB
    __shared__ __attribute__((aligned(16))) unsigned short Esh[64][72];      // 9.2 KB
    __shared__ float stj[64];
    __shared__ float dsred[2][64];

    const int t    = threadIdx.x;
    const int w    = t >> 6;
    const int lane = t & 63;
    const int quad = lane >> 4;
    const int l16  = lane & 15;

    const int b   = blockIdx.x >> 6;
    const int it0 = (blockIdx.x & 63) << 6;

    const unsigned short* Vbb = Vb + (size_t)b * N_ * D_;
    const unsigned short* VTb = VT + (size_t)b * D_ * N_;
    const float*          stb = state + (size_t)b * N_;

    const int hi  = lane >> 5;   // 0/1
    const int p32 = lane & 31;
    const int dr8 = lane >> 3;   // 0..7
    const int p8  = lane & 7;

    // per-lane global element offsets (ushort units), loop-invariant parts
    int vgoff[8];   // vi/vj row-pair loads
    int tgoff[8];   // vjt loads
    #pragma unroll
    for (int n = 0; n < 8; ++n) {
        int r = 2 * (w * 8 + n) + hi;            // 0..63 row within tile
        int g = p32 ^ (r & 7);
        vgoff[n] = r * 256 + g * 8;
        int d = 8 * (w * 8 + n) + dr8;           // 0..255
        int gt = p8 ^ dr8;
        tgoff[n] = d * 4096 + gt * 8;
    }

    // ---- prologue: stage vi, vj(0), vjt(0)->buf0, stj(0) ----
    #pragma unroll
    for (int n = 0; n < 8; ++n)
        gl_lds16(Vbb + (size_t)it0 * 256 + vgoff[n], &vi[(w * 8 + n) * 512]);
    #pragma unroll
    for (int n = 0; n < 8; ++n)
        gl_lds16(Vbb + vgoff[n], &vj[(w * 8 + n) * 512]);
    #pragma unroll
    for (int n = 0; n < 8; ++n)
        gl_lds16(VTb + tgoff[n], &vjt[(w * 8 + n) * 512]);
    if (w == 0) gl_lds4(stb + lane, &stj[0]);
    __syncthreads();

    const int r0 = (w >> 1) * 32;
    const int c0 = (w & 1) * 32;
    const int pA = l16 & 7;      // row-derived xor component (row&7 == l16&7 here)

    floatx4 dv[4][4];
    #pragma unroll
    for (int a = 0; a < 4; ++a)
        #pragma unroll
        for (int c = 0; c < 4; ++c)
            dv[a][c] = (floatx4){0.f, 0.f, 0.f, 0.f};
    float dsp[8];
    #pragma unroll
    for (int k = 0; k < 8; ++k) dsp[k] = 0.f;

    for (int k = 0; k < 64; ++k) {
        const int buf = k & 1;

        // ---- GEMM1: S[64][64] = Vi . Vj^T (K = 256) ----
        floatx4 sa[2][2];
        #pragma unroll
        for (int a = 0; a < 2; ++a)
            #pragma unroll
            for (int c = 0; c < 2; ++c)
                sa[a][c] = (floatx4){0.f, 0.f, 0.f, 0.f};

        #pragma unroll
        for (int ks = 0; ks < 8; ++ks) {
            const int p = ((ks * 4 + quad) ^ pA) * 8;
            short8 a0 = *(const short8*)&vi[(r0 + l16) * 256 + p];
            short8 a1 = *(const short8*)&vi[(r0 + 16 + l16) * 256 + p];
            short8 b0 = *(const short8*)&vj[(c0 + l16) * 256 + p];
            short8 b1 = *(const short8*)&vj[(c0 + 16 + l16) * 256 + p];
            sa[0][0] = __builtin_amdgcn_mfma_f32_16x16x32_bf16(a0, b0, sa[0][0], 0, 0, 0);
            sa[0][1] = __builtin_amdgcn_mfma_f32_16x16x32_bf16(a0, b1, sa[0][1], 0, 0, 0);
            sa[1][0] = __builtin_amdgcn_mfma_f32_16x16x32_bf16(a1, b0, sa[1][0], 0, 0, 0);
            sa[1][1] = __builtin_amdgcn_mfma_f32_16x16x32_bf16(a1, b1, sa[1][1], 0, 0, 0);
        }

        // ---- softsign epilogue -> Esh + delta_state partials ----
        float stc0 = stj[c0 + l16];
        float stc1 = stj[c0 + 16 + l16];
        #pragma unroll
        for (int a = 0; a < 2; ++a) {
            #pragma unroll
            for (int r = 0; r < 4; ++r) {
                const int il = r0 + a * 16 + quad * 4 + r;
                float s0 = sa[a][0][r] * 0.0625f;
                float s1 = sa[a][1][r] * 0.0625f;
                float e0 = s0 * __builtin_amdgcn_rcpf(1.0f + fabsf(s0));
                float e1 = s1 * __builtin_amdgcn_rcpf(1.0f + fabsf(s1));
                dsp[a * 4 + r] += e0 * stc0 + e1 * stc1;
                Esh[il][c0 + l16]      = f2bf(e0);
                Esh[il][c0 + 16 + l16] = f2bf(e1);
            }
        }
        __syncthreads();   // B2: Esh ready; vj/stj consumed; vjt buf^1 free

        // ---- async-stage next tile (hidden behind GEMM2) ----
        if (k < 63) {
            const int j0n = (k + 1) * 64;
            #pragma unroll
            for (int n = 0; n < 8; ++n)
                gl_lds16(Vbb + (size_t)j0n * 256 + vgoff[n], &vj[(w * 8 + n) * 512]);
            #pragma unroll
            for (int n = 0; n < 8; ++n)
                gl_lds16(VTb + (size_t)j0n + tgoff[n],
                         &vjt[(buf ^ 1) * 16384 + (w * 8 + n) * 512]);
            if (w == 0) gl_lds4(stb + j0n + lane, &stj[0]);
        }

        // ---- GEMM2: dval[64][256] += E[64][64] . Vj[64][256] (K = 64) ----
        #pragma unroll
        for (int ks = 0; ks < 2; ++ks) {
            short8 af[4], bfr[4];
            #pragma unroll
            for (int a2 = 0; a2 < 4; ++a2)
                af[a2] = *(const short8*)&Esh[a2 * 16 + l16][ks * 32 + quad * 8];
            #pragma unroll
            for (int c2 = 0; c2 < 4; ++c2) {
                const int d = w * 64 + c2 * 16 + l16;
                const int p = ((ks * 4 + quad) ^ (l16 & 7)) * 8;
                bfr[c2] = *(const short8*)&vjt[buf * 16384 + d * 64 + p];
            }
            #pragma unroll
            for (int a2 = 0; a2 < 4; ++a2)
                #pragma unroll
                for (int c2 = 0; c2 < 4; ++c2)
                    dv[a2][c2] = __builtin_amdgcn_mfma_f32_16x16x32_bf16(af[a2], bfr[c2], dv[a2][c2], 0, 0, 0);
        }
        __syncthreads();   // B1: drains staging vmcnt + ds reads; next GEMM1 safe
    }

    // ---- epilogue: delta_val ----
    float* dvo = out + (size_t)B_ * N_ + (size_t)b * N_ * D_;
    #pragma unroll
    for (int a2 = 0; a2 < 4; ++a2)
        #pragma unroll
        for (int c2 = 0; c2 < 4; ++c2)
            #pragma unroll
            for (int r = 0; r < 4; ++r) {
                const int i = it0 + a2 * 16 + quad * 4 + r;
                const int d = w * 64 + c2 * 16 + l16;
                dvo[(size_t)i * D_ + d] = dv[a2][c2][r];
            }

    // ---- epilogue: delta_state ----
    #pragma unroll
    for (int k = 0; k < 8; ++k) {
        float v = dsp[k];
        v += __shfl_xor(v, 1);
        v += __shfl_xor(v, 2);
        v += __shfl_xor(v, 4);
        v += __shfl_xor(v, 8);
        dsp[k] = v;
    }
    if (l16 == 0) {
        #pragma unroll
        for (int a = 0; a < 2; ++a)
            #pragma unroll
            for (int r = 0; r < 4; ++r) {
                const int row = (w >> 1) * 32 + a * 16 + quad * 4 + r;
                dsred[w & 1][row] = dsp[a * 4 + r];
            }
    }
    __syncthreads();
    if (t < 64) out[(size_t)b * N_ + it0 + t] = dsred[0][t] + dsred[1][t];
}

// ---------------- fallback (round-1 kernel, used if ws too small) ----------------
__global__ __launch_bounds__(256, 1)
void prop_kernel_fb(const float* __restrict__ val,
                    const float* __restrict__ state,
                    float* __restrict__ out) {
    __shared__ __attribute__((aligned(16))) unsigned short vi[64][264];
    __shared__ __attribute__((aligned(16))) unsigned short vj[64][264];
    __shared__ __attribute__((aligned(16))) unsigned short vjt[2048][8];
    __shared__ __attribute__((aligned(16))) unsigned short Esh[64][72];
    __shared__ float stj[64];
    __shared__ float dsred[2][64];

    const int t    = threadIdx.x;
    const int w    = t >> 6;
    const int lane = t & 63;
    const int quad = lane >> 4;
    const int l16  = lane & 15;
    const int b   = blockIdx.x >> 6;
    const int it0 = (blockIdx.x & 63) << 6;
    const float* valb = val   + (size_t)b * N_ * D_;
    const float* stb  = state + (size_t)b * N_;

    #pragma unroll
    for (int n = 0; n < 16; ++n) {
        int idx = t + 256 * n;
        int row = idx >> 6;
        int c4  = idx & 63;
        float4 v = *(const float4*)(valb + (size_t)(it0 + row) * D_ + c4 * 4);
        ushort4 h;
        h.x = f2bf(v.x); h.y = f2bf(v.y); h.z = f2bf(v.z); h.w = f2bf(v.w);
        *(ushort4*)&vi[row][c4 * 4] = h;
    }

    const int r0 = (w >> 1) * 32;
    const int c0 = (w & 1) * 32;
    floatx4 dv[4][4];
    #pragma unroll
    for (int a = 0; a < 4; ++a)
        #pragma unroll
        for (int c = 0; c < 4; ++c)
            dv[a][c] = (floatx4){0.f, 0.f, 0.f, 0.f};
    float dsp[8];
    #pragma unroll
    for (int k = 0; k < 8; ++k) dsp[k] = 0.f;

    for (int jt = 0; jt < 64; ++jt) {
        const int j0 = jt * 64;
        #pragma unroll
        for (int n = 0; n < 16; ++n) {
            int idx = t + 256 * n;
            int row = idx >> 6;
            int c4  = idx & 63;
            float4 v = *(const float4*)(valb + (size_t)(j0 + row) * D_ + c4 * 4);
            ushort4 h;
            h.x = f2bf(v.x); h.y = f2bf(v.y); h.z = f2bf(v.z); h.w = f2bf(v.w);
            *(ushort4*)&vj[row][c4 * 4] = h;
        }
        if (t < 64) stj[t] = stb[j0 + t];
        __syncthreads();

        #pragma unroll
        for (int n = 0; n < 8; ++n) {
            const int d  = t;
            const int jb = n;
            short8 pk;
            #pragma unroll
            for (int jj = 0; jj < 8; ++jj) pk[jj] = (short)vj[jb * 8 + jj][d];
            *(short8*)&vjt[d * 8 + (jb ^ (d & 7))][0] = pk;
        }

        floatx4 sa[2][2];
        #pragma unroll
        for (int a = 0; a < 2; ++a)
            #pragma unroll
            for (int c = 0; c < 2; ++c)
                sa[a][c] = (floatx4){0.f, 0.f, 0.f, 0.f};
        #pragma unroll
        for (int ks = 0; ks < 8; ++ks) {
            const int d0 = ks * 32 + quad * 8;
            short8 a0 = *(const short8*)&vi[r0 + l16][d0];
            short8 a1 = *(const short8*)&vi[r0 + 16 + l16][d0];
            short8 b0 = *(const short8*)&vj[c0 + l16][d0];
            short8 b1 = *(const short8*)&vj[c0 + 16 + l16][d0];
            sa[0][0] = __builtin_amdgcn_mfma_f32_16x16x32_bf16(a0, b0, sa[0][0], 0, 0, 0);
            sa[0][1] = __builtin_amdgcn_mfma_f32_16x16x32_bf16(a0, b1, sa[0][1], 0, 0, 0);
            sa[1][0] = __builtin_amdgcn_mfma_f32_16x16x32_bf16(a1, b0, sa[1][0], 0, 0, 0);
            sa[1][1] = __builtin_amdgcn_mfma_f32_16x16x32_bf16(a1, b1, sa[1][1], 0, 0, 0);
        }

        float stc0 = stj[c0 + l16];
        float stc1 = stj[c0 + 16 + l16];
        #pragma unroll
        for (int a = 0; a < 2; ++a) {
            #pragma unroll
            for (int r = 0; r < 4; ++r) {
                const int il = r0 + a * 16 + quad * 4 + r;
                float s0 = sa[a][0][r] * 0.0625f;
                float s1 = sa[a][1][r] * 0.0625f;
                float e0 = s0 / (1.0f + fabsf(s0));
                float e1 = s1 / (1.0f + fabsf(s1));
                dsp[a * 4 + r] += e0 * stc0 + e1 * stc1;
                Esh[il][c0 + l16]      = f2bf(e0);
                Esh[il][c0 + 16 + l16] = f2bf(e1);
            }
        }
        __syncthreads();

        #pragma unroll
        for (int ks = 0; ks < 2; ++ks) {
            short8 af[4], bfr[4];
            #pragma unroll
            for (int a2 = 0; a2 < 4; ++a2)
                af[a2] = *(const short8*)&Esh[a2 * 16 + l16][ks * 32 + quad * 8];
            #pragma unroll
            for (int c2 = 0; c2 < 4; ++c2) {
                const int d  = w * 64 + c2 * 16 + l16;
                const int jb = ks * 4 + quad;
                bfr[c2] = *(const short8*)&vjt[d * 8 + (jb ^ (d & 7))][0];
            }
            #pragma unroll
            for (int a2 = 0; a2 < 4; ++a2)
                #pragma unroll
                for (int c2 = 0; c2 < 4; ++c2)
                    dv[a2][c2] = __builtin_amdgcn_mfma_f32_16x16x32_bf16(af[a2], bfr[c2], dv[a2][c2], 0, 0, 0);
        }
    }

    float* dvo = out + (size_t)B_ * N_ + (size_t)b * N_ * D_;
    #pragma unroll
    for (int a2 = 0; a2 < 4; ++a2)
        #pragma unroll
        for (int c2 = 0; c2 < 4; ++c2)
            #pragma unroll
            for (int r = 0; r < 4; ++r) {
                const int i = it0 + a2 * 16 + quad * 4 + r;
                const int d = w * 64 + c2 * 16 + l16;
                dvo[(size_t)i * D_ + d] = dv[a2][c2][r];
            }

    #pragma unroll
    for (int k = 0; k < 8; ++k) {
        float v = dsp[k];
        v += __shfl_xor(v, 1);
        v += __shfl_xor(v, 2);
        v += __shfl_xor(v, 4);
        v += __shfl_xor(v, 8);
        dsp[k] = v;
    }
    if (l16 == 0) {
        #pragma unroll
        for (int a = 0; a < 2; ++a)
            #pragma unroll
            for (int r = 0; r < 4; ++r) {
                const int row = (w >> 1) * 32 + a * 16 + quad * 4 + r;
                dsred[w & 1][row] = dsp[a * 4 + r];
            }
    }
    __syncthreads();
    if (t < 64) out[(size_t)b * N_ + it0 + t] = dsred[0][t] + dsred[1][t];
}

extern "C" void kernel_launch(void* const* d_in, const int* in_sizes, int n_in,
                              void* d_out, int out_size, void* d_ws, size_t ws_size,
                              hipStream_t stream) {
    const float* val   = (const float*)d_in[0];
    const float* state = (const float*)d_in[1];
    float* out = (float*)d_out;
    const size_t need = (size_t)2 * B_ * N_ * D_ * sizeof(unsigned short); // 16 MB
    if (ws_size >= need) {
        unsigned short* Vb = (unsigned short*)d_ws;
        unsigned short* VT = Vb + (size_t)B_ * N_ * D_;
        prepass_kernel<<<dim3(1024), dim3(256), 0, stream>>>(val, Vb, VT);
        prop_main<<<dim3(256), dim3(256), 0, stream>>>(state, Vb, VT, out);
    } else {
        prop_kernel_fb<<<dim3(256), dim3(256), 0, stream>>>(val, state, out);
    }
}

// Round 3
// 162.664 us; speedup vs baseline: 1.6649x; 1.3003x over previous
//
#include <hip/hip_runtime.h>

// Propagation: E = softsign(V V^T / sqrt(D)); out0 = E @ state; out1 = E @ V
// B=4, N=4096, D=256, fp32 in/out.
//
// Round 3:
//  - prepass: val fp32 -> Vb bf16 [B][N][D] and VT bf16 [B][D][N] in d_ws.
//  - main: A-fragments of the i-tile hoisted to registers (64 VGPRs, loaded
//    once from Vb) -> vi LDS buffer deleted; LDS = vj 32K + vjt 32K (single
//    buffer) + Esh 9.2K = 75.5 KB -> 2 blocks/CU. Grid 512 via j-range split
//    (each block does 32 of 64 j-tiles); partial dval/dstate in d_ws, small
//    combine kernel sums the two halves. 3 barriers/iter.
//  - fallbacks: no-split (ws >= 17MB) and fully-fused round-1 kernel.

#define B_  4
#define N_  4096
#define D_  256

typedef __attribute__((ext_vector_type(8))) short short8;
typedef __attribute__((ext_vector_type(4))) float floatx4;

__device__ __forceinline__ unsigned short f2bf(float f) {
    unsigned int u = __float_as_uint(f);
    u += 0x7fff + ((u >> 16) & 1);   // RTNE
    return (unsigned short)(u >> 16);
}

__device__ __forceinline__ void gl_lds16(const void* g, void* l) {
    __builtin_amdgcn_global_load_lds(
        (const __attribute__((address_space(1))) unsigned int*)g,
        (__attribute__((address_space(3))) unsigned int*)l, 16, 0, 0);
}
__device__ __forceinline__ void gl_lds4(const void* g, void* l) {
    __builtin_amdgcn_global_load_lds(
        (const __attribute__((address_space(1))) unsigned int*)g,
        (__attribute__((address_space(3))) unsigned int*)l, 4, 0, 0);
}

// ---------------- pre-pass: fp32 -> bf16, plus transpose ----------------
__global__ __launch_bounds__(256)
void prepass_kernel(const float* __restrict__ val,
                    unsigned short* __restrict__ Vb,
                    unsigned short* __restrict__ VT) {
    __shared__ unsigned short tile[64][68];
    const int t   = threadIdx.x;
    const int blk = blockIdx.x;            // b*256 + it*4 + dt
    const int b   = blk >> 8;
    const int it  = (blk >> 2) & 63;
    const int dt  = blk & 3;
    const int i0  = it * 64, d0 = dt * 64;
    const float*    vb  = val + (size_t)b * N_ * D_;
    unsigned short* Vbb = Vb  + (size_t)b * N_ * D_;
    unsigned short* VTb = VT  + (size_t)b * D_ * N_;

    #pragma unroll
    for (int q = 0; q < 4; ++q) {
        int idx = t + 256 * q;
        int row = idx >> 4;
        int c4  = idx & 15;
        float4 v = *(const float4*)(vb + (size_t)(i0 + row) * D_ + d0 + c4 * 4);
        ushort4 h;
        h.x = f2bf(v.x); h.y = f2bf(v.y); h.z = f2bf(v.z); h.w = f2bf(v.w);
        *(ushort4*)(Vbb + (size_t)(i0 + row) * D_ + d0 + c4 * 4) = h;
        *(ushort4*)&tile[row][c4 * 4] = h;
    }
    __syncthreads();
    #pragma unroll
    for (int q = 0; q < 4; ++q) {
        int dr = (t >> 4) + q * 16;
        int i4 = t & 15;
        ushort4 h;
        h.x = tile[i4 * 4 + 0][dr];
        h.y = tile[i4 * 4 + 1][dr];
        h.z = tile[i4 * 4 + 2][dr];
        h.w = tile[i4 * 4 + 3][dr];
        *(ushort4*)(VTb + (size_t)(d0 + dr) * N_ + i0 + i4 * 4) = h;
    }
}

// ---------------- main fused kernel ----------------
// split==0: grid 256 (b*64+it), full j range, dvout/dsout point into out.
// split==1: grid 512 (b*128 + it*2 + h), half j range, partials in ws.
__global__ __launch_bounds__(256, 2)
void prop_main(const float* __restrict__ state,
               const unsigned short* __restrict__ Vb,
               const unsigned short* __restrict__ VT,
               float* __restrict__ dvout,
               float* __restrict__ dsout,
               int split) {
    __shared__ __attribute__((aligned(16))) unsigned short vj[64 * 256];   // 32 KB
    __shared__ __attribute__((aligned(16))) unsigned short vjt[16384];     // 32 KB
    __shared__ __attribute__((aligned(16))) unsigned short Esh[64][72];    // 9.2 KB
    __shared__ float stj[64];
    __shared__ float dsred[2][64];

    const int t    = threadIdx.x;
    const int w    = t >> 6;
    const int lane = t & 63;
    const int quad = lane >> 4;
    const int l16  = lane & 15;

    int b, it0, h, niter;
    if (split) {
        h   = blockIdx.x & 1;
        it0 = ((blockIdx.x >> 1) & 63) << 6;
        b   = blockIdx.x >> 7;
        niter = 32;
    } else {
        h   = 0;
        it0 = (blockIdx.x & 63) << 6;
        b   = blockIdx.x >> 6;
        niter = 64;
    }
    const int jbase = h * 2048;

    const unsigned short* Vbb = Vb + (size_t)b * N_ * D_;
    const unsigned short* VTb = VT + (size_t)b * D_ * N_;
    const float*          stb = state + (size_t)b * N_;

    const int hi  = lane >> 5;
    const int p32 = lane & 31;
    const int dr8 = lane >> 3;
    const int p8  = lane & 7;

    int vgoff[8];   // vj row-pair load offsets (ushort units)
    int tgoff[8];   // vjt load offsets
    #pragma unroll
    for (int n = 0; n < 8; ++n) {
        int r = 2 * (w * 8 + n) + hi;
        int g = p32 ^ (r & 7);
        vgoff[n] = r * 256 + g * 8;
        int d = 8 * (w * 8 + n) + dr8;
        int gt = p8 ^ dr8;
        tgoff[n] = d * 4096 + gt * 8;
    }

    const int r0 = (w >> 1) * 32;
    const int c0 = (w & 1) * 32;
    const int pA = l16 & 7;

    // ---- hoist GEMM1 A-fragments to registers (loop-invariant) ----
    short8 A0[8], A1[8];
    {
        const unsigned short* ar0 = Vbb + (size_t)(it0 + r0 + l16) * 256 + quad * 8;
        const unsigned short* ar1 = ar0 + 16 * 256;
        #pragma unroll
        for (int ks = 0; ks < 8; ++ks) {
            A0[ks] = *(const short8*)(ar0 + ks * 32);
            A1[ks] = *(const short8*)(ar1 + ks * 32);
        }
    }

    // ---- prologue staging ----
    #pragma unroll
    for (int n = 0; n < 8; ++n)
        gl_lds16(Vbb + (size_t)jbase * 256 + vgoff[n], &vj[(w * 8 + n) * 512]);
    if (w == 0) gl_lds4(stb + jbase + lane, &stj[0]);
    #pragma unroll
    for (int n = 0; n < 8; ++n)
        gl_lds16(VTb + (size_t)jbase + tgoff[n], &vjt[(w * 8 + n) * 512]);

    floatx4 dv[4][4];
    #pragma unroll
    for (int a = 0; a < 4; ++a)
        #pragma unroll
        for (int c = 0; c < 4; ++c)
            dv[a][c] = (floatx4){0.f, 0.f, 0.f, 0.f};
    float dsp[8];
    #pragma unroll
    for (int k = 0; k < 8; ++k) dsp[k] = 0.f;

    for (int k = 0; k < niter; ++k) {
        __syncthreads();   // B1: staged vj/vjt/stj visible

        // ---- GEMM1: S = Vi . Vj^T (A from registers) ----
        floatx4 sa[2][2];
        #pragma unroll
        for (int a = 0; a < 2; ++a)
            #pragma unroll
            for (int c = 0; c < 2; ++c)
                sa[a][c] = (floatx4){0.f, 0.f, 0.f, 0.f};

        #pragma unroll
        for (int ks = 0; ks < 8; ++ks) {
            const int p = ((ks * 4 + quad) ^ pA) * 8;
            short8 b0 = *(const short8*)&vj[(c0 + l16) * 256 + p];
            short8 b1 = *(const short8*)&vj[(c0 + 16 + l16) * 256 + p];
            sa[0][0] = __builtin_amdgcn_mfma_f32_16x16x32_bf16(A0[ks], b0, sa[0][0], 0, 0, 0);
            sa[0][1] = __builtin_amdgcn_mfma_f32_16x16x32_bf16(A0[ks], b1, sa[0][1], 0, 0, 0);
            sa[1][0] = __builtin_amdgcn_mfma_f32_16x16x32_bf16(A1[ks], b0, sa[1][0], 0, 0, 0);
            sa[1][1] = __builtin_amdgcn_mfma_f32_16x16x32_bf16(A1[ks], b1, sa[1][1], 0, 0, 0);
        }

        // ---- softsign epilogue -> Esh + delta_state partials ----
        float stc0 = stj[c0 + l16];
        float stc1 = stj[c0 + 16 + l16];
        #pragma unroll
        for (int a = 0; a < 2; ++a) {
            #pragma unroll
            for (int r = 0; r < 4; ++r) {
                const int il = r0 + a * 16 + quad * 4 + r;
                float s0 = sa[a][0][r] * 0.0625f;
                float s1 = sa[a][1][r] * 0.0625f;
                float e0 = s0 * __builtin_amdgcn_rcpf(1.0f + fabsf(s0));
                float e1 = s1 * __builtin_amdgcn_rcpf(1.0f + fabsf(s1));
                dsp[a * 4 + r] += e0 * stc0 + e1 * stc1;
                Esh[il][c0 + l16]      = f2bf(e0);
                Esh[il][c0 + 16 + l16] = f2bf(e1);
            }
        }
        __syncthreads();   // B2: Esh visible; vj/stj fully consumed

        // ---- stage next vj/stj (hidden behind GEMM2) ----
        if (k + 1 < niter) {
            const size_t j0n = jbase + (size_t)(k + 1) * 64;
            #pragma unroll
            for (int n = 0; n < 8; ++n)
                gl_lds16(Vbb + j0n * 256 + vgoff[n], &vj[(w * 8 + n) * 512]);
            if (w == 0) gl_lds4(stb + j0n + lane, &stj[0]);
        }

        // ---- GEMM2: dval += E . Vj ----
        #pragma unroll
        for (int ks = 0; ks < 2; ++ks) {
            short8 af[4], bfr[4];
            #pragma unroll
            for (int a2 = 0; a2 < 4; ++a2)
                af[a2] = *(const short8*)&Esh[a2 * 16 + l16][ks * 32 + quad * 8];
            #pragma unroll
            for (int c2 = 0; c2 < 4; ++c2) {
                const int d = w * 64 + c2 * 16 + l16;
                const int p = ((ks * 4 + quad) ^ (l16 & 7)) * 8;
                bfr[c2] = *(const short8*)&vjt[d * 64 + p];
            }
            #pragma unroll
            for (int a2 = 0; a2 < 4; ++a2)
                #pragma unroll
                for (int c2 = 0; c2 < 4; ++c2)
                    dv[a2][c2] = __builtin_amdgcn_mfma_f32_16x16x32_bf16(af[a2], bfr[c2], dv[a2][c2], 0, 0, 0);
        }
        __syncthreads();   // B3: vjt/Esh fully consumed

        // ---- stage next vjt ----
        if (k + 1 < niter) {
            const size_t j0n = jbase + (size_t)(k + 1) * 64;
            #pragma unroll
            for (int n = 0; n < 8; ++n)
                gl_lds16(VTb + j0n + tgoff[n], &vjt[(w * 8 + n) * 512]);
        }
    }

    // ---- epilogue: delta_val (partial or final) ----
    float* dvo = dvout + (size_t)h * B_ * N_ * D_ + (size_t)b * N_ * D_;
    #pragma unroll
    for (int a2 = 0; a2 < 4; ++a2)
        #pragma unroll
        for (int c2 = 0; c2 < 4; ++c2)
            #pragma unroll
            for (int r = 0; r < 4; ++r) {
                const int i = it0 + a2 * 16 + quad * 4 + r;
                const int d = w * 64 + c2 * 16 + l16;
                dvo[(size_t)i * D_ + d] = dv[a2][c2][r];
            }

    // ---- epilogue: delta_state ----
    #pragma unroll
    for (int k = 0; k < 8; ++k) {
        float v = dsp[k];
        v += __shfl_xor(v, 1);
        v += __shfl_xor(v, 2);
        v += __shfl_xor(v, 4);
        v += __shfl_xor(v, 8);
        dsp[k] = v;
    }
    if (l16 == 0) {
        #pragma unroll
        for (int a = 0; a < 2; ++a)
            #pragma unroll
            for (int r = 0; r < 4; ++r) {
                const int row = (w >> 1) * 32 + a * 16 + quad * 4 + r;
                dsred[w & 1][row] = dsp[a * 4 + r];
            }
    }
    __syncthreads();
    if (t < 64)
        dsout[(size_t)h * B_ * N_ + (size_t)b * N_ + it0 + t] = dsred[0][t] + dsred[1][t];
}

// ---------------- combine: out = sum of the two j-half partials ----------------
__global__ __launch_bounds__(256)
void combine_kernel(const float4* __restrict__ dv0, const float4* __restrict__ dv1,
                    const float*  __restrict__ ds0, const float*  __restrict__ ds1,
                    float* __restrict__ out) {
    const int NDV4 = B_ * N_ * D_ / 4;   // 1048576
    const int NDS  = B_ * N_;            // 16384
    int x = blockIdx.x * 256 + threadIdx.x;
    if (x < NDV4) {
        float4 a = dv0[x], c = dv1[x];
        float4 r;
        r.x = a.x + c.x; r.y = a.y + c.y; r.z = a.z + c.z; r.w = a.w + c.w;
        ((float4*)(out + NDS))[x] = r;
    } else {
        int y = (x - NDV4) * 4;
        if (y < NDS) {
            float4 a = *(const float4*)(ds0 + y);
            float4 c = *(const float4*)(ds1 + y);
            float4 r;
            r.x = a.x + c.x; r.y = a.y + c.y; r.z = a.z + c.z; r.w = a.w + c.w;
            *(float4*)(out + y) = r;
        }
    }
}

// ---------------- fallback (round-1 kernel, used if ws too small) ----------------
__global__ __launch_bounds__(256, 1)
void prop_kernel_fb(const float* __restrict__ val,
                    const float* __restrict__ state,
                    float* __restrict__ out) {
    __shared__ __attribute__((aligned(16))) unsigned short vi[64][264];
    __shared__ __attribute__((aligned(16))) unsigned short vj[64][264];
    __shared__ __attribute__((aligned(16))) unsigned short vjt[2048][8];
    __shared__ __attribute__((aligned(16))) unsigned short Esh[64][72];
    __shared__ float stj[64];
    __shared__ float dsred[2][64];

    const int t    = threadIdx.x;
    const int w    = t >> 6;
    const int lane = t & 63;
    const int quad = lane >> 4;
    const int l16  = lane & 15;
    const int b   = blockIdx.x >> 6;
    const int it0 = (blockIdx.x & 63) << 6;
    const float* valb = val   + (size_t)b * N_ * D_;
    const float* stb  = state + (size_t)b * N_;

    #pragma unroll
    for (int n = 0; n < 16; ++n) {
        int idx = t + 256 * n;
        int row = idx >> 6;
        int c4  = idx & 63;
        float4 v = *(const float4*)(valb + (size_t)(it0 + row) * D_ + c4 * 4);
        ushort4 h;
        h.x = f2bf(v.x); h.y = f2bf(v.y); h.z = f2bf(v.z); h.w = f2bf(v.w);
        *(ushort4*)&vi[row][c4 * 4] = h;
    }

    const int r0 = (w >> 1) * 32;
    const int c0 = (w & 1) * 32;
    floatx4 dv[4][4];
    #pragma unroll
    for (int a = 0; a < 4; ++a)
        #pragma unroll
        for (int c = 0; c < 4; ++c)
            dv[a][c] = (floatx4){0.f, 0.f, 0.f, 0.f};
    float dsp[8];
    #pragma unroll
    for (int k = 0; k < 8; ++k) dsp[k] = 0.f;

    for (int jt = 0; jt < 64; ++jt) {
        const int j0 = jt * 64;
        #pragma unroll
        for (int n = 0; n < 16; ++n) {
            int idx = t + 256 * n;
            int row = idx >> 6;
            int c4  = idx & 63;
            float4 v = *(const float4*)(valb + (size_t)(j0 + row) * D_ + c4 * 4);
            ushort4 h;
            h.x = f2bf(v.x); h.y = f2bf(v.y); h.z = f2bf(v.z); h.w = f2bf(v.w);
            *(ushort4*)&vj[row][c4 * 4] = h;
        }
        if (t < 64) stj[t] = stb[j0 + t];
        __syncthreads();

        #pragma unroll
        for (int n = 0; n < 8; ++n) {
            const int d  = t;
            const int jb = n;
            short8 pk;
            #pragma unroll
            for (int jj = 0; jj < 8; ++jj) pk[jj] = (short)vj[jb * 8 + jj][d];
            *(short8*)&vjt[d * 8 + (jb ^ (d & 7))][0] = pk;
        }

        floatx4 sa[2][2];
        #pragma unroll
        for (int a = 0; a < 2; ++a)
            #pragma unroll
            for (int c = 0; c < 2; ++c)
                sa[a][c] = (floatx4){0.f, 0.f, 0.f, 0.f};
        #pragma unroll
        for (int ks = 0; ks < 8; ++ks) {
            const int d0 = ks * 32 + quad * 8;
            short8 a0 = *(const short8*)&vi[r0 + l16][d0];
            short8 a1 = *(const short8*)&vi[r0 + 16 + l16][d0];
            short8 b0 = *(const short8*)&vj[c0 + l16][d0];
            short8 b1 = *(const short8*)&vj[c0 + 16 + l16][d0];
            sa[0][0] = __builtin_amdgcn_mfma_f32_16x16x32_bf16(a0, b0, sa[0][0], 0, 0, 0);
            sa[0][1] = __builtin_amdgcn_mfma_f32_16x16x32_bf16(a0, b1, sa[0][1], 0, 0, 0);
            sa[1][0] = __builtin_amdgcn_mfma_f32_16x16x32_bf16(a1, b0, sa[1][0], 0, 0, 0);
            sa[1][1] = __builtin_amdgcn_mfma_f32_16x16x32_bf16(a1, b1, sa[1][1], 0, 0, 0);
        }

        float stc0 = stj[c0 + l16];
        float stc1 = stj[c0 + 16 + l16];
        #pragma unroll
        for (int a = 0; a < 2; ++a) {
            #pragma unroll
            for (int r = 0; r < 4; ++r) {
                const int il = r0 + a * 16 + quad * 4 + r;
                float s0 = sa[a][0][r] * 0.0625f;
                float s1 = sa[a][1][r] * 0.0625f;
                float e0 = s0 / (1.0f + fabsf(s0));
                float e1 = s1 / (1.0f + fabsf(s1));
                dsp[a * 4 + r] += e0 * stc0 + e1 * stc1;
                Esh[il][c0 + l16]      = f2bf(e0);
                Esh[il][c0 + 16 + l16] = f2bf(e1);
            }
        }
        __syncthreads();

        #pragma unroll
        for (int ks = 0; ks < 2; ++ks) {
            short8 af[4], bfr[4];
            #pragma unroll
            for (int a2 = 0; a2 < 4; ++a2)
                af[a2] = *(const short8*)&Esh[a2 * 16 + l16][ks * 32 + quad * 8];
            #pragma unroll
            for (int c2 = 0; c2 < 4; ++c2) {
                const int d  = w * 64 + c2 * 16 + l16;
                const int jb = ks * 4 + quad;
                bfr[c2] = *(const short8*)&vjt[d * 8 + (jb ^ (d & 7))][0];
            }
            #pragma unroll
            for (int a2 = 0; a2 < 4; ++a2)
                #pragma unroll
                for (int c2 = 0; c2 < 4; ++c2)
                    dv[a2][c2] = __builtin_amdgcn_mfma_f32_16x16x32_bf16(af[a2], bfr[c2], dv[a2][c2], 0, 0, 0);
        }
    }

    float* dvo = out + (size_t)B_ * N_ + (size_t)b * N_ * D_;
    #pragma unroll
    for (int a2 = 0; a2 < 4; ++a2)
        #pragma unroll
        for (int c2 = 0; c2 < 4; ++c2)
            #pragma unroll
            for (int r = 0; r < 4; ++r) {
                const int i = it0 + a2 * 16 + quad * 4 + r;
                const int d = w * 64 + c2 * 16 + l16;
                dvo[(size_t)i * D_ + d] = dv[a2][c2][r];
            }

    #pragma unroll
    for (int k = 0; k < 8; ++k) {
        float v = dsp[k];
        v += __shfl_xor(v, 1);
        v += __shfl_xor(v, 2);
        v += __shfl_xor(v, 4);
        v += __shfl_xor(v, 8);
        dsp[k] = v;
    }
    if (l16 == 0) {
        #pragma unroll
        for (int a = 0; a < 2; ++a)
            #pragma unroll
            for (int r = 0; r < 4; ++r) {
                const int row = (w >> 1) * 32 + a * 16 + quad * 4 + r;
                dsred[w & 1][row] = dsp[a * 4 + r];
            }
    }
    __syncthreads();
    if (t < 64) out[(size_t)b * N_ + it0 + t] = dsred[0][t] + dsred[1][t];
}

extern "C" void kernel_launch(void* const* d_in, const int* in_sizes, int n_in,
                              void* d_out, int out_size, void* d_ws, size_t ws_size,
                              hipStream_t stream) {
    const float* val   = (const float*)d_in[0];
    const float* state = (const float*)d_in[1];
    float* out = (float*)d_out;

    const size_t nE        = (size_t)B_ * N_ * D_;                 // 4,194,304
    const size_t need_base = 2 * nE * sizeof(unsigned short);      // 16.78 MB
    const size_t need_split = need_base + 2 * nE * sizeof(float)
                            + 2 * (size_t)B_ * N_ * sizeof(float); // ~50.5 MB

    if (ws_size >= need_base) {
        unsigned short* Vb = (unsigned short*)d_ws;
        unsigned short* VT = Vb + nE;
        prepass_kernel<<<dim3(1024), dim3(256), 0, stream>>>(val, Vb, VT);
        if (ws_size >= need_split) {
            float* dvp = (float*)(VT + nE);          // 2 * nE floats
            float* dsp = dvp + 2 * nE;               // 2 * B*N floats
            prop_main<<<dim3(512), dim3(256), 0, stream>>>(state, Vb, VT, dvp, dsp, 1);
            const int NDV4 = B_ * N_ * D_ / 4;
            const int NDS4 = B_ * N_ / 4;
            combine_kernel<<<dim3((NDV4 + NDS4) / 256), dim3(256), 0, stream>>>(
                (const float4*)dvp, (const float4*)(dvp + nE),
                dsp, dsp + (size_t)B_ * N_, out);
        } else {
            prop_main<<<dim3(256), dim3(256), 0, stream>>>(
                state, Vb, VT, out + (size_t)B_ * N_, out, 0);
        }
    } else {
        prop_kernel_fb<<<dim3(256), dim3(256), 0, stream>>>(val, state, out);
    }
}

// Round 4
// 157.167 us; speedup vs baseline: 1.7231x; 1.0350x over previous
//
#include <hip/hip_runtime.h>

// Propagation: E = softsign(V V^T / sqrt(D)); out0 = E @ state; out1 = E @ V
// B=4, N=4096, D=256, fp32 in/out.
//
// Round 4:
//  - prepass: val fp32 -> Vb bf16 [B][N][D] and VT bf16 [B][D][N] in d_ws.
//  - main: ONE 512-thread block per (b, i-tile): two wave-groups of 4 waves,
//    each runs the round-3 loop on half the j range in its own LDS region
//    (2 x 75.5 KB). Final in-block reduce: group 1 dumps dv into LDS
//    (overlay of its vj/vjt, stride 260 -> 2-way conflicts only), barrier,
//    group 0 adds + stores. Eliminates the combine kernel, one launch
//    boundary, and the 50 MB partial round-trip.
//  - fallback: round-1 fused kernel if ws too small.

#define B_  4
#define N_  4096
#define D_  256

typedef __attribute__((ext_vector_type(8))) short short8;
typedef __attribute__((ext_vector_type(4))) float floatx4;

__device__ __forceinline__ unsigned short f2bf(float f) {
    unsigned int u = __float_as_uint(f);
    u += 0x7fff + ((u >> 16) & 1);   // RTNE
    return (unsigned short)(u >> 16);
}

__device__ __forceinline__ void gl_lds16(const void* g, void* l) {
    __builtin_amdgcn_global_load_lds(
        (const __attribute__((address_space(1))) unsigned int*)g,
        (__attribute__((address_space(3))) unsigned int*)l, 16, 0, 0);
}
__device__ __forceinline__ void gl_lds4(const void* g, void* l) {
    __builtin_amdgcn_global_load_lds(
        (const __attribute__((address_space(1))) unsigned int*)g,
        (__attribute__((address_space(3))) unsigned int*)l, 4, 0, 0);
}

// ---------------- pre-pass: fp32 -> bf16, plus transpose ----------------
__global__ __launch_bounds__(256)
void prepass_kernel(const float* __restrict__ val,
                    unsigned short* __restrict__ Vb,
                    unsigned short* __restrict__ VT) {
    __shared__ unsigned short tile[64][68];
    const int t   = threadIdx.x;
    const int blk = blockIdx.x;            // b*256 + it*4 + dt
    const int b   = blk >> 8;
    const int it  = (blk >> 2) & 63;
    const int dt  = blk & 3;
    const int i0  = it * 64, d0 = dt * 64;
    const float*    vb  = val + (size_t)b * N_ * D_;
    unsigned short* Vbb = Vb  + (size_t)b * N_ * D_;
    unsigned short* VTb = VT  + (size_t)b * D_ * N_;

    #pragma unroll
    for (int q = 0; q < 4; ++q) {
        int idx = t + 256 * q;
        int row = idx >> 4;
        int c4  = idx & 15;
        float4 v = *(const float4*)(vb + (size_t)(i0 + row) * D_ + d0 + c4 * 4);
        ushort4 h;
        h.x = f2bf(v.x); h.y = f2bf(v.y); h.z = f2bf(v.z); h.w = f2bf(v.w);
        *(ushort4*)(Vbb + (size_t)(i0 + row) * D_ + d0 + c4 * 4) = h;
        *(ushort4*)&tile[row][c4 * 4] = h;
    }
    __syncthreads();
    #pragma unroll
    for (int q = 0; q < 4; ++q) {
        int dr = (t >> 4) + q * 16;
        int i4 = t & 15;
        ushort4 h;
        h.x = tile[i4 * 4 + 0][dr];
        h.y = tile[i4 * 4 + 1][dr];
        h.z = tile[i4 * 4 + 2][dr];
        h.w = tile[i4 * 4 + 3][dr];
        *(ushort4*)(VTb + (size_t)(d0 + dr) * N_ + i0 + i4 * 4) = h;
    }
}

// ---------------- main fused kernel: 512 threads, 2 wave-groups ----------------
// Per-group LDS region (75520 B):
//   vj   @     0 : 64*256 bf16 = 32768 B
//   vjt  @ 32768 : 16384 bf16  = 32768 B
//   Esh  @ 65536 : 64*72 bf16  =  9216 B
//   stj  @ 74752 : 64 f32      =   256 B
//   dsred@ 75008 : 2*64 f32    =   512 B
// Epilogue overlay: dvred (f32 [64][260] = 66560 B) at group-1 base (< 75008).
#define GRP_STRIDE 75520

__global__ __launch_bounds__(512, 1)
void prop_main(const float* __restrict__ state,
               const unsigned short* __restrict__ Vb,
               const unsigned short* __restrict__ VT,
               float* __restrict__ out) {
    __shared__ __attribute__((aligned(16))) unsigned char smem[2 * GRP_STRIDE];

    const int t    = threadIdx.x;
    const int g    = t >> 8;          // wave-group 0/1
    const int tg   = t & 255;
    const int w    = tg >> 6;         // wave within group, 0..3
    const int lane = t & 63;
    const int quad = lane >> 4;
    const int l16  = lane & 15;

    unsigned short* vjg   = (unsigned short*)(smem + g * GRP_STRIDE);
    unsigned short* vjtg  = (unsigned short*)(smem + g * GRP_STRIDE + 32768);
    unsigned short* Eshg  = (unsigned short*)(smem + g * GRP_STRIDE + 65536);
    float*          stjg  = (float*)(smem + g * GRP_STRIDE + 74752);
    float*          dsredg= (float*)(smem + g * GRP_STRIDE + 75008);

    const int b   = blockIdx.x >> 6;
    const int it0 = (blockIdx.x & 63) << 6;
    const int jbase = g * 2048;
    const int niter = 32;

    const unsigned short* Vbb = Vb + (size_t)b * N_ * D_;
    const unsigned short* VTb = VT + (size_t)b * D_ * N_;
    const float*          stb = state + (size_t)b * N_;

    const int hi  = lane >> 5;
    const int p32 = lane & 31;
    const int dr8 = lane >> 3;
    const int p8  = lane & 7;

    int vgoff[8];   // vj row-pair load offsets (ushort units)
    int tgoff[8];   // vjt load offsets
    #pragma unroll
    for (int n = 0; n < 8; ++n) {
        int r = 2 * (w * 8 + n) + hi;
        int gg = p32 ^ (r & 7);
        vgoff[n] = r * 256 + gg * 8;
        int d = 8 * (w * 8 + n) + dr8;
        int gt = p8 ^ dr8;
        tgoff[n] = d * 4096 + gt * 8;
    }

    const int r0 = (w >> 1) * 32;
    const int c0 = (w & 1) * 32;
    const int pA = l16 & 7;

    // ---- hoist GEMM1 A-fragments to registers (loop-invariant) ----
    short8 A0[8], A1[8];
    {
        const unsigned short* ar0 = Vbb + (size_t)(it0 + r0 + l16) * 256 + quad * 8;
        const unsigned short* ar1 = ar0 + 16 * 256;
        #pragma unroll
        for (int ks = 0; ks < 8; ++ks) {
            A0[ks] = *(const short8*)(ar0 + ks * 32);
            A1[ks] = *(const short8*)(ar1 + ks * 32);
        }
    }

    // ---- prologue staging ----
    #pragma unroll
    for (int n = 0; n < 8; ++n)
        gl_lds16(Vbb + (size_t)jbase * 256 + vgoff[n], &vjg[(w * 8 + n) * 512]);
    if (w == 0) gl_lds4(stb + jbase + lane, &stjg[0]);
    #pragma unroll
    for (int n = 0; n < 8; ++n)
        gl_lds16(VTb + (size_t)jbase + tgoff[n], &vjtg[(w * 8 + n) * 512]);

    floatx4 dv[4][4];
    #pragma unroll
    for (int a = 0; a < 4; ++a)
        #pragma unroll
        for (int c = 0; c < 4; ++c)
            dv[a][c] = (floatx4){0.f, 0.f, 0.f, 0.f};
    float dsp[8];
    #pragma unroll
    for (int k = 0; k < 8; ++k) dsp[k] = 0.f;

    for (int k = 0; k < niter; ++k) {
        __syncthreads();   // B1: staged vj/vjt/stj visible

        // ---- GEMM1: S = Vi . Vj^T (A from registers) ----
        floatx4 sa[2][2];
        #pragma unroll
        for (int a = 0; a < 2; ++a)
            #pragma unroll
            for (int c = 0; c < 2; ++c)
                sa[a][c] = (floatx4){0.f, 0.f, 0.f, 0.f};

        #pragma unroll
        for (int ks = 0; ks < 8; ++ks) {
            const int p = ((ks * 4 + quad) ^ pA) * 8;
            short8 b0 = *(const short8*)&vjg[(c0 + l16) * 256 + p];
            short8 b1 = *(const short8*)&vjg[(c0 + 16 + l16) * 256 + p];
            sa[0][0] = __builtin_amdgcn_mfma_f32_16x16x32_bf16(A0[ks], b0, sa[0][0], 0, 0, 0);
            sa[0][1] = __builtin_amdgcn_mfma_f32_16x16x32_bf16(A0[ks], b1, sa[0][1], 0, 0, 0);
            sa[1][0] = __builtin_amdgcn_mfma_f32_16x16x32_bf16(A1[ks], b0, sa[1][0], 0, 0, 0);
            sa[1][1] = __builtin_amdgcn_mfma_f32_16x16x32_bf16(A1[ks], b1, sa[1][1], 0, 0, 0);
        }

        // ---- softsign epilogue -> Esh + delta_state partials ----
        float stc0 = stjg[c0 + l16];
        float stc1 = stjg[c0 + 16 + l16];
        #pragma unroll
        for (int a = 0; a < 2; ++a) {
            #pragma unroll
            for (int r = 0; r < 4; ++r) {
                const int il = r0 + a * 16 + quad * 4 + r;
                float s0 = sa[a][0][r] * 0.0625f;
                float s1 = sa[a][1][r] * 0.0625f;
                float e0 = s0 * __builtin_amdgcn_rcpf(1.0f + fabsf(s0));
                float e1 = s1 * __builtin_amdgcn_rcpf(1.0f + fabsf(s1));
                dsp[a * 4 + r] += e0 * stc0 + e1 * stc1;
                Eshg[il * 72 + c0 + l16]      = f2bf(e0);
                Eshg[il * 72 + c0 + 16 + l16] = f2bf(e1);
            }
        }
        __syncthreads();   // B2: Esh visible; vj/stj fully consumed

        // ---- stage next vj/stj (hidden behind GEMM2) ----
        if (k + 1 < niter) {
            const size_t j0n = jbase + (size_t)(k + 1) * 64;
            #pragma unroll
            for (int n = 0; n < 8; ++n)
                gl_lds16(Vbb + j0n * 256 + vgoff[n], &vjg[(w * 8 + n) * 512]);
            if (w == 0) gl_lds4(stb + j0n + lane, &stjg[0]);
        }

        // ---- GEMM2: dval += E . Vj ----
        #pragma unroll
        for (int ks = 0; ks < 2; ++ks) {
            short8 af[4], bfr[4];
            #pragma unroll
            for (int a2 = 0; a2 < 4; ++a2)
                af[a2] = *(const short8*)&Eshg[(a2 * 16 + l16) * 72 + ks * 32 + quad * 8];
            #pragma unroll
            for (int c2 = 0; c2 < 4; ++c2) {
                const int d = w * 64 + c2 * 16 + l16;
                const int p = ((ks * 4 + quad) ^ (l16 & 7)) * 8;
                bfr[c2] = *(const short8*)&vjtg[d * 64 + p];
            }
            #pragma unroll
            for (int a2 = 0; a2 < 4; ++a2)
                #pragma unroll
                for (int c2 = 0; c2 < 4; ++c2)
                    dv[a2][c2] = __builtin_amdgcn_mfma_f32_16x16x32_bf16(af[a2], bfr[c2], dv[a2][c2], 0, 0, 0);
        }
        __syncthreads();   // B3: vjt/Esh fully consumed

        // ---- stage next vjt ----
        if (k + 1 < niter) {
            const size_t j0n = jbase + (size_t)(k + 1) * 64;
            #pragma unroll
            for (int n = 0; n < 8; ++n)
                gl_lds16(VTb + j0n + tgoff[n], &vjtg[(w * 8 + n) * 512]);
        }
    }

    // ---- delta_state per-group reduction (both groups, before barrier) ----
    #pragma unroll
    for (int k = 0; k < 8; ++k) {
        float v = dsp[k];
        v += __shfl_xor(v, 1);
        v += __shfl_xor(v, 2);
        v += __shfl_xor(v, 4);
        v += __shfl_xor(v, 8);
        dsp[k] = v;
    }
    if (l16 == 0) {
        #pragma unroll
        for (int a = 0; a < 2; ++a)
            #pragma unroll
            for (int r = 0; r < 4; ++r) {
                const int row = (w >> 1) * 32 + a * 16 + quad * 4 + r;
                dsredg[(w & 1) * 64 + row] = dsp[a * 4 + r];
            }
    }

    // ---- group 1 dumps dv into LDS (overlay of its vj/vjt region) ----
    float* dvred = (float*)(smem + GRP_STRIDE);   // [64][260]
    if (g == 1) {
        #pragma unroll
        for (int a2 = 0; a2 < 4; ++a2)
            #pragma unroll
            for (int c2 = 0; c2 < 4; ++c2)
                #pragma unroll
                for (int r = 0; r < 4; ++r) {
                    const int i = a2 * 16 + quad * 4 + r;
                    const int d = w * 64 + c2 * 16 + l16;
                    dvred[i * 260 + d] = dv[a2][c2][r];
                }
    }
    __syncthreads();   // dvred + both dsred visible

    if (g == 0) {
        // ---- final delta_val: dv(group0) + dvred(group1) -> out ----
        float* dvo = out + (size_t)B_ * N_ + (size_t)b * N_ * D_;
        #pragma unroll
        for (int a2 = 0; a2 < 4; ++a2)
            #pragma unroll
            for (int c2 = 0; c2 < 4; ++c2)
                #pragma unroll
                for (int r = 0; r < 4; ++r) {
                    const int il = a2 * 16 + quad * 4 + r;
                    const int d  = w * 64 + c2 * 16 + l16;
                    dvo[(size_t)(it0 + il) * D_ + d] = dv[a2][c2][r] + dvred[il * 260 + d];
                }
        // ---- final delta_state: sum the 4 dsred arrays ----
        if (t < 64) {
            const float* ds0 = (const float*)(smem + 75008);
            const float* ds1 = (const float*)(smem + GRP_STRIDE + 75008);
            out[(size_t)b * N_ + it0 + t] = ds0[t] + ds0[64 + t] + ds1[t] + ds1[64 + t];
        }
    }
}

// ---------------- fallback (round-1 kernel, used if ws too small) ----------------
__global__ __launch_bounds__(256, 1)
void prop_kernel_fb(const float* __restrict__ val,
                    const float* __restrict__ state,
                    float* __restrict__ out) {
    __shared__ __attribute__((aligned(16))) unsigned short vi[64][264];
    __shared__ __attribute__((aligned(16))) unsigned short vj[64][264];
    __shared__ __attribute__((aligned(16))) unsigned short vjt[2048][8];
    __shared__ __attribute__((aligned(16))) unsigned short Esh[64][72];
    __shared__ float stj[64];
    __shared__ float dsred[2][64];

    const int t    = threadIdx.x;
    const int w    = t >> 6;
    const int lane = t & 63;
    const int quad = lane >> 4;
    const int l16  = lane & 15;
    const int b   = blockIdx.x >> 6;
    const int it0 = (blockIdx.x & 63) << 6;
    const float* valb = val   + (size_t)b * N_ * D_;
    const float* stb  = state + (size_t)b * N_;

    #pragma unroll
    for (int n = 0; n < 16; ++n) {
        int idx = t + 256 * n;
        int row = idx >> 6;
        int c4  = idx & 63;
        float4 v = *(const float4*)(valb + (size_t)(it0 + row) * D_ + c4 * 4);
        ushort4 h;
        h.x = f2bf(v.x); h.y = f2bf(v.y); h.z = f2bf(v.z); h.w = f2bf(v.w);
        *(ushort4*)&vi[row][c4 * 4] = h;
    }

    const int r0 = (w >> 1) * 32;
    const int c0 = (w & 1) * 32;
    floatx4 dv[4][4];
    #pragma unroll
    for (int a = 0; a < 4; ++a)
        #pragma unroll
        for (int c = 0; c < 4; ++c)
            dv[a][c] = (floatx4){0.f, 0.f, 0.f, 0.f};
    float dsp[8];
    #pragma unroll
    for (int k = 0; k < 8; ++k) dsp[k] = 0.f;

    for (int jt = 0; jt < 64; ++jt) {
        const int j0 = jt * 64;
        #pragma unroll
        for (int n = 0; n < 16; ++n) {
            int idx = t + 256 * n;
            int row = idx >> 6;
            int c4  = idx & 63;
            float4 v = *(const float4*)(valb + (size_t)(j0 + row) * D_ + c4 * 4);
            ushort4 h;
            h.x = f2bf(v.x); h.y = f2bf(v.y); h.z = f2bf(v.z); h.w = f2bf(v.w);
            *(ushort4*)&vj[row][c4 * 4] = h;
        }
        if (t < 64) stj[t] = stb[j0 + t];
        __syncthreads();

        #pragma unroll
        for (int n = 0; n < 8; ++n) {
            const int d  = t;
            const int jb = n;
            short8 pk;
            #pragma unroll
            for (int jj = 0; jj < 8; ++jj) pk[jj] = (short)vj[jb * 8 + jj][d];
            *(short8*)&vjt[d * 8 + (jb ^ (d & 7))][0] = pk;
        }

        floatx4 sa[2][2];
        #pragma unroll
        for (int a = 0; a < 2; ++a)
            #pragma unroll
            for (int c = 0; c < 2; ++c)
                sa[a][c] = (floatx4){0.f, 0.f, 0.f, 0.f};
        #pragma unroll
        for (int ks = 0; ks < 8; ++ks) {
            const int d0 = ks * 32 + quad * 8;
            short8 a0 = *(const short8*)&vi[r0 + l16][d0];
            short8 a1 = *(const short8*)&vi[r0 + 16 + l16][d0];
            short8 b0 = *(const short8*)&vj[c0 + l16][d0];
            short8 b1 = *(const short8*)&vj[c0 + 16 + l16][d0];
            sa[0][0] = __builtin_amdgcn_mfma_f32_16x16x32_bf16(a0, b0, sa[0][0], 0, 0, 0);
            sa[0][1] = __builtin_amdgcn_mfma_f32_16x16x32_bf16(a0, b1, sa[0][1], 0, 0, 0);
            sa[1][0] = __builtin_amdgcn_mfma_f32_16x16x32_bf16(a1, b0, sa[1][0], 0, 0, 0);
            sa[1][1] = __builtin_amdgcn_mfma_f32_16x16x32_bf16(a1, b1, sa[1][1], 0, 0, 0);
        }

        float stc0 = stj[c0 + l16];
        float stc1 = stj[c0 + 16 + l16];
        #pragma unroll
        for (int a = 0; a < 2; ++a) {
            #pragma unroll
            for (int r = 0; r < 4; ++r) {
                const int il = r0 + a * 16 + quad * 4 + r;
                float s0 = sa[a][0][r] * 0.0625f;
                float s1 = sa[a][1][r] * 0.0625f;
                float e0 = s0 / (1.0f + fabsf(s0));
                float e1 = s1 / (1.0f + fabsf(s1));
                dsp[a * 4 + r] += e0 * stc0 + e1 * stc1;
                Esh[il][c0 + l16]      = f2bf(e0);
                Esh[il][c0 + 16 + l16] = f2bf(e1);
            }
        }
        __syncthreads();

        #pragma unroll
        for (int ks = 0; ks < 2; ++ks) {
            short8 af[4], bfr[4];
            #pragma unroll
            for (int a2 = 0; a2 < 4; ++a2)
                af[a2] = *(const short8*)&Esh[a2 * 16 + l16][ks * 32 + quad * 8];
            #pragma unroll
            for (int c2 = 0; c2 < 4; ++c2) {
                const int d  = w * 64 + c2 * 16 + l16;
                const int jb = ks * 4 + quad;
                bfr[c2] = *(const short8*)&vjt[d * 8 + (jb ^ (d & 7))][0];
            }
            #pragma unroll
            for (int a2 = 0; a2 < 4; ++a2)
                #pragma unroll
                for (int c2 = 0; c2 < 4; ++c2)
                    dv[a2][c2] = __builtin_amdgcn_mfma_f32_16x16x32_bf16(af[a2], bfr[c2], dv[a2][c2], 0, 0, 0);
        }
    }

    float* dvo = out + (size_t)B_ * N_ + (size_t)b * N_ * D_;
    #pragma unroll
    for (int a2 = 0; a2 < 4; ++a2)
        #pragma unroll
        for (int c2 = 0; c2 < 4; ++c2)
            #pragma unroll
            for (int r = 0; r < 4; ++r) {
                const int i = it0 + a2 * 16 + quad * 4 + r;
                const int d = w * 64 + c2 * 16 + l16;
                dvo[(size_t)i * D_ + d] = dv[a2][c2][r];
            }

    #pragma unroll
    for (int k = 0; k < 8; ++k) {
        float v = dsp[k];
        v += __shfl_xor(v, 1);
        v += __shfl_xor(v, 2);
        v += __shfl_xor(v, 4);
        v += __shfl_xor(v, 8);
        dsp[k] = v;
    }
    if (l16 == 0) {
        #pragma unroll
        for (int a = 0; a < 2; ++a)
            #pragma unroll
            for (int r = 0; r < 4; ++r) {
                const int row = (w >> 1) * 32 + a * 16 + quad * 4 + r;
                dsred[w & 1][row] = dsp[a * 4 + r];
            }
    }
    __syncthreads();
    if (t < 64) out[(size_t)b * N_ + it0 + t] = dsred[0][t] + dsred[1][t];
}

extern "C" void kernel_launch(void* const* d_in, const int* in_sizes, int n_in,
                              void* d_out, int out_size, void* d_ws, size_t ws_size,
                              hipStream_t stream) {
    const float* val   = (const float*)d_in[0];
    const float* state = (const float*)d_in[1];
    float* out = (float*)d_out;

    const size_t nE   = (size_t)B_ * N_ * D_;              // 4,194,304
    const size_t need = 2 * nE * sizeof(unsigned short);   // 16.78 MB

    if (ws_size >= need) {
        unsigned short* Vb = (unsigned short*)d_ws;
        unsigned short* VT = Vb + nE;
        prepass_kernel<<<dim3(1024), dim3(256), 0, stream>>>(val, Vb, VT);
        prop_main<<<dim3(256), dim3(512), 0, stream>>>(state, Vb, VT, out);
    } else {
        prop_kernel_fb<<<dim3(256), dim3(256), 0, stream>>>(val, state, out);
    }
}